// Round 3
// baseline (1436.227 us; speedup 1.0000x reference)
//
#include <hip/hip_runtime.h>
#include <math.h>

// Problem constants
#define QTOT   512
#define CDIM   256
#define HDIM   1024
#define NROWS  500000
#define NB     128
#define NTILES ((NROWS + NB - 1) / NB)   // 3907
#define NGRP   (NTILES * 8)              // 31256 16-row groups
#define LDB    264                       // bf16 row stride in LDS (k_gemm + fallback)
#define DELTA  2.0f

// chunking of the codebook for the conv+coarse passes
#define C0_T   1954                      // tiles in chunk 0
#define C1_T   (NTILES - C0_T)           // 1953
#define C0_R   (C0_T * NB)               // 250112 rows
#define C1_R   (C1_T * NB)               // 249984 rows (includes pad tail)

typedef short bf16x8 __attribute__((ext_vector_type(8)));
typedef float f32x4  __attribute__((ext_vector_type(4)));
typedef unsigned int u32;

__device__ __forceinline__ unsigned short bf16_rne(float f) {
  unsigned u = __float_as_uint(f);
  u += 0x7FFFu + ((u >> 16) & 1u);
  return (unsigned short)(u >> 16);
}
__device__ __forceinline__ unsigned bfp2(float a, float b) {
  return (unsigned)bf16_rne(a) | ((unsigned)bf16_rne(b) << 16);
}

// async global->LDS, 16B per lane; lds dest wave-uniform base (lane*16 implicit)
__device__ __forceinline__ void gld16(const void* g, void* l) {
  __builtin_amdgcn_global_load_lds((const __attribute__((address_space(1))) u32*)g,
                                   (__attribute__((address_space(3))) u32*)l, 16, 0, 0);
}

// DPP reductions within 16-lane rows (VALU-speed, no LDS pipe)
#define FMIN_DPP(x, ctrl) do { \
    int _t = __builtin_amdgcn_update_dpp(__float_as_int(x), __float_as_int(x), (ctrl), 0xF, 0xF, false); \
    x = fminf(x, __int_as_float(_t)); } while (0)
#define FADD_DPP(x, ctrl) do { \
    int _t = __builtin_amdgcn_update_dpp(__float_as_int(x), __float_as_int(x), (ctrl), 0xF, 0xF, false); \
    x += __int_as_float(_t); } while (0)

// ---------------------------------------------------------------- K0: codes -> bf16(-2c), MFMA-frag swizzled
// frag layout: [qb(4)][m(8)][ks(8)][lane(64)][8 bf16]; lane = quad*16 + l15
// lane l of frag (qb,m,ks) holds A[q = qb*128 + m*16 + (l&15)][k = ks*32 + (l>>4)*8 + off]
__global__ void k_prep(const float* __restrict__ codes, unsigned short* __restrict__ a0s) {
  int q = blockIdx.x, k = threadIdx.x;
  float v = -2.0f * codes[q * CDIM + k];
  int qb = q >> 7, row = q & 127, m = row >> 4, l15 = row & 15;
  int ks = k >> 5, kin = k & 31, quad = kin >> 3, off = kin & 7;
  int lane = quad * 16 + l15;
  a0s[(((qb * 8 + m) * 8 + ks) * 64 + lane) * 8 + off] = bf16_rne(v);
}

// ---------------------------------------------------------------- K_conv: fp32 codebook chunk -> bf16 rows + fp32 ||cb||^2
// linear bf16 layout: cbh[r][256], row stride 512 B. pad rows -> zeros, c2 = 1e30.
__global__ __launch_bounds__(256) void k_conv(
    const float* __restrict__ cb, unsigned short* __restrict__ cbh,
    float* __restrict__ c2, int row0, int nrows)
{
  const int lane = threadIdx.x & 63;
  const int wid  = (blockIdx.x * 256 + threadIdx.x) >> 6;
  const int nw   = (gridDim.x * 256) >> 6;
  for (int r = wid; r < nrows; r += nw) {
    const int gr = row0 + r;
    float4 v = make_float4(0.f, 0.f, 0.f, 0.f);
    if (gr < NROWS) v = *(const float4*)(cb + (size_t)gr * CDIM + lane * 4);
    float sq = v.x * v.x + v.y * v.y + v.z * v.z + v.w * v.w;
    FADD_DPP(sq, 0xB1);   // quad_perm xor1
    FADD_DPP(sq, 0x4E);   // quad_perm xor2
    FADD_DPP(sq, 0x124);  // row_ror:4
    FADD_DPP(sq, 0x128);  // row_ror:8
    sq += __shfl_xor(sq, 16);
    sq += __shfl_xor(sq, 32);
    uint2 p; p.x = bfp2(v.x, v.y); p.y = bfp2(v.z, v.w);
    *(uint2*)((char*)cbh + (size_t)r * 512 + lane * 8) = p;
    if (lane == 0) c2[r] = (gr < NROWS) ? sq : 1e30f;
  }
}

// ---------------------------------------------------------------- K1 v4: persistent blocks, A-in-registers, dbuf half-tiles
// 512 threads = 8 waves; wave w owns q in [w*64, w*64+64) with its A-frags held in
// 128 VGPRs for the WHOLE kernel (zero A re-reads). Block processes tiles
// bid + k*gridDim strided; each 64-row half-tile staged via global_load_lds into
// a 32KB double buffer with counted s_waitcnt vmcnt(4) (loads fly across barriers).
// Outputs: groupMin[g][512] per 16-row group; tileMin[q][NTILES] via LDS fold.
__device__ __forceinline__ void stage_half(const unsigned short* __restrict__ cbh,
                                           int ntl, int h, unsigned short* buf,
                                           int w, int lane) {
  const char* tb = (const char*)cbh + (size_t)ntl * 65536 + h * 32768;
  const int lrow0 = w * 8;
  const int cS = lane & 31;
  const int rpar = lane >> 5;
#pragma unroll
  for (int i2 = 0; i2 < 4; ++i2) {
    const int lrow = lrow0 + i2 * 2 + rpar;
    gld16(tb + (size_t)lrow * 512 + ((cS ^ (lrow & 7)) << 4),
          (char*)buf + (lrow0 + i2 * 2) * 512);
  }
}

__global__ __launch_bounds__(512, 2) void k_coarse(
    const unsigned short* __restrict__ a0s,
    const unsigned short* __restrict__ cbh,
    const float* __restrict__ c2arr,
    float* __restrict__ tileMin,
    float* __restrict__ groupMin,
    int nt0, int ctiles)
{
  __shared__ __align__(16) unsigned short Bsh[2][64 * 256];  // 2 x 32 KB
  __shared__ float c2sh[8 * 128];                            // 4 KB
  __shared__ float hb[8][512];                               // 16 KB tile-min fold

  const int tid  = threadIdx.x;
  const int lane = tid & 63;
  const int w    = tid >> 6;        // 0..7: q-group
  const int quad = lane >> 4;
  const int l15  = lane & 15;
  const int bid  = blockIdx.x;
  const int NBL  = gridDim.x;

  const int myT = (ctiles - bid + NBL - 1) / NBL;   // tiles for this block

  for (int i = tid; i < myT * 128; i += 512)
    c2sh[i] = c2arr[(bid + (i >> 7) * NBL) * 128 + (i & 127)];

  // A fragments: wave w covers q = w*64 + m*16 + l15 -> qb = w>>1, mfrag = (w&1)*4+m
  bf16x8 afr[4][8];
  {
    const unsigned short* base = a0s + ((w >> 1) * 8 + (w & 1) * 4) * 4096 + lane * 8;
#pragma unroll
    for (int m = 0; m < 4; ++m)
#pragma unroll
      for (int ks = 0; ks < 8; ++ks)
        afr[m][ks] = *(const bf16x8*)(base + (m * 8 + ks) * 512);
  }

  stage_half(cbh, bid, 0, Bsh[0], w, lane);
  __syncthreads();   // prologue: full drain (c2sh, afr, first half staged)

  const int nh = myT * 2;
  for (int hh = 0; hh < nh; ++hh) {
    const int k = hh >> 1, h = hh & 1, buf = hh & 1;

    if (hh + 1 < nh) {   // issue next half-tile, keep 4 loads in flight across barrier
      stage_half(cbh, bid + ((hh + 1) >> 1) * NBL, (hh + 1) & 1, Bsh[buf ^ 1], w, lane);
      asm volatile("s_waitcnt vmcnt(4)" ::: "memory");
    } else {
      asm volatile("s_waitcnt vmcnt(0)" ::: "memory");
    }
    __builtin_amdgcn_s_barrier();
    __builtin_amdgcn_sched_barrier(0);

    float cadd[4];
#pragma unroll
    for (int j2 = 0; j2 < 4; ++j2)
      cadd[j2] = c2sh[k * 128 + h * 64 + j2 * 16 + l15];

    f32x4 acc[4][4];
#pragma unroll
    for (int m = 0; m < 4; ++m)
#pragma unroll
      for (int j2 = 0; j2 < 4; ++j2) acc[m][j2] = (f32x4){0.f, 0.f, 0.f, 0.f};

#pragma unroll
    for (int ks = 0; ks < 8; ++ks) {
      bf16x8 b[4];
#pragma unroll
      for (int j2 = 0; j2 < 4; ++j2) {
        const int lrow = j2 * 16 + l15;
        b[j2] = *(const bf16x8*)((const char*)Bsh[buf] + lrow * 512 + (((ks * 4 + quad) ^ (lrow & 7)) << 4));
      }
#pragma unroll
      for (int m = 0; m < 4; ++m)
#pragma unroll
        for (int j2 = 0; j2 < 4; ++j2)
          acc[m][j2] = __builtin_amdgcn_mfma_f32_16x16x32_bf16(afr[m][ks], b[j2], acc[m][j2], 0, 0, 0);
    }

    // epilogue: per-q 16-row group mins (DPP over l15 = n-within-group)
    const int ntg = nt0 + bid + k * NBL;
#pragma unroll
    for (int m = 0; m < 4; ++m) {
#pragma unroll
      for (int r = 0; r < 4; ++r) {
        float g4[4];
#pragma unroll
        for (int j2 = 0; j2 < 4; ++j2) {
          float kk = acc[m][j2][r] + cadd[j2];
          FMIN_DPP(kk, 0xB1);   // xor1
          FMIN_DPP(kk, 0x4E);   // xor2
          FMIN_DPP(kk, 0x124);  // ror4
          FMIN_DPP(kk, 0x128);  // ror8
          g4[j2] = kk;
        }
        float hmin = fminf(fminf(g4[0], g4[1]), fminf(g4[2], g4[3]));
        if (l15 == 0) {
          const int q = w * 64 + m * 16 + quad * 4 + r;
#pragma unroll
          for (int j2 = 0; j2 < 4; ++j2)
            groupMin[(size_t)(ntg * 8 + h * 4 + j2) * 512 + q] = g4[j2];
          hb[k][q] = h ? fminf(hb[k][q], hmin) : hmin;
        }
      }
    }
    __builtin_amdgcn_s_barrier();
    __builtin_amdgcn_sched_barrier(0);
  }

  __syncthreads();
  for (int k = 0; k < myT; ++k)
    tileMin[(size_t)tid * NTILES + (nt0 + bid + k * NBL)] = hb[k][tid];
}

// ---------------------------------------------------------------- K1 fallback (reads fp32 cb; tile-granularity only)
__global__ __launch_bounds__(256, 2) void k_coarse_fb(
    const unsigned short* __restrict__ a0s,
    const float* __restrict__ cb,
    float* __restrict__ tileMin)
{
  __shared__ __align__(16) unsigned short Bsh[128 * 256];
  __shared__ float c2sh[128];
  __shared__ float redf[512 * 2];

  const int tid  = threadIdx.x;
  const int lane = tid & 63;
  const int w    = tid >> 6;
  const int quad = lane >> 4;
  const int l15  = lane & 15;

  const int nt = blockIdx.x;
  const int n0 = nt * NB;

  const int wq = (w >> 1) * 64;
  const int wn = (w & 1) * 64;

#pragma unroll 8
  for (int j = 0; j < 32; ++j) {
    int f = j * 256 + tid;
    int row = f >> 6;
    int c4  = f & 63;
    int n   = n0 + row;
    float4 v = make_float4(0.f, 0.f, 0.f, 0.f);
    if (n < NROWS) v = *(const float4*)(cb + (size_t)n * CDIM + c4 * 4);
    float sq = v.x * v.x + v.y * v.y + v.z * v.z + v.w * v.w;
    uint2 p; p.x = bfp2(v.x, v.y); p.y = bfp2(v.z, v.w);
    int chunk = (c4 >> 1) ^ (row & 7);
    *(uint2*)((char*)Bsh + row * 512 + chunk * 16 + (c4 & 1) * 8) = p;
#pragma unroll
    for (int s = 32; s; s >>= 1) sq += __shfl_xor(sq, s);
    if (lane == 0) c2sh[row] = (n < NROWS) ? sq : 1e30f;
  }
  __syncthreads();

  float cadd[4];
#pragma unroll
  for (int j2 = 0; j2 < 4; ++j2) cadd[j2] = c2sh[wn + j2 * 16 + l15];

  for (int qb = 0; qb < 4; ++qb) {
    bf16x8 afr[4][8];
    {
      const int mg0 = (w >> 1) * 4;
      const unsigned short* base = a0s + (size_t)(qb * 8 + mg0) * 8 * 64 * 8 + lane * 8;
#pragma unroll
      for (int m = 0; m < 4; ++m)
#pragma unroll
        for (int ks = 0; ks < 8; ++ks)
          afr[m][ks] = *(const bf16x8*)(base + (m * 8 + ks) * 64 * 8);
    }
    f32x4 acc[4][4];
#pragma unroll
    for (int m = 0; m < 4; ++m)
#pragma unroll
      for (int j2 = 0; j2 < 4; ++j2) acc[m][j2] = (f32x4){0.f, 0.f, 0.f, 0.f};
#pragma unroll
    for (int ks = 0; ks < 8; ++ks) {
      bf16x8 b[4];
      const int cbase = ks * 4 + quad;
#pragma unroll
      for (int j2 = 0; j2 < 4; ++j2) {
        const int row = wn + j2 * 16 + l15;
        b[j2] = *(const bf16x8*)((const char*)Bsh + row * 512 + ((cbase ^ (row & 7)) << 4));
      }
#pragma unroll
      for (int m = 0; m < 4; ++m)
#pragma unroll
        for (int j2 = 0; j2 < 4; ++j2)
          acc[m][j2] = __builtin_amdgcn_mfma_f32_16x16x32_bf16(afr[m][ks], b[j2], acc[m][j2], 0, 0, 0);
    }
#pragma unroll
    for (int m = 0; m < 4; ++m) {
#pragma unroll
      for (int r = 0; r < 4; ++r) {
        float kk = 1e30f;
#pragma unroll
        for (int j2 = 0; j2 < 4; ++j2) kk = fminf(kk, acc[m][j2][r] + cadd[j2]);
#pragma unroll
        for (int s = 1; s < 16; s <<= 1) kk = fminf(kk, __shfl_xor(kk, s));
        if (l15 == 0) redf[(qb * 128 + wq + m * 16 + quad * 4 + r) * 2 + (w & 1)] = kk;
      }
    }
  }
  __syncthreads();

#pragma unroll
  for (int qq = 0; qq < 2; ++qq) {
    int q = qq * 256 + tid;
    tileMin[(size_t)q * NTILES + nt] = fminf(redf[q * 2], redf[q * 2 + 1]);
  }
}

// ---------------------------------------------------------------- K2: exact refine + gather prev
// groupMin != null: candidates at 16-row group granularity (8x less exact traffic)
__global__ __launch_bounds__(256) void k_refine(
    const float* __restrict__ codes, const float* __restrict__ cb,
    const float* __restrict__ tileMin, const float* __restrict__ groupMin,
    float* __restrict__ prev)
{
#define LCAP 256
  __shared__ float csh[256];
  __shared__ float red[256];
  __shared__ int   list[LCAP];
  __shared__ int   cnt;
  __shared__ double rd[256];
  __shared__ int    rn[256];

  const int q = blockIdx.x;
  const int tid = threadIdx.x;
  csh[tid] = codes[q * CDIM + tid];
  if (tid == 0) cnt = 0;
  const float* tm = tileMin + (size_t)q * NTILES;
  float lm = 1e30f;
  for (int t = tid; t < NTILES; t += 256) lm = fminf(lm, tm[t]);
  red[tid] = lm;
  __syncthreads();
  for (int s = 128; s; s >>= 1) {
    if (tid < s) red[tid] = fminf(red[tid], red[tid + s]);
    __syncthreads();
  }
  const float thresh = red[0] + DELTA;

  if (groupMin) {
    for (int t = tid; t < NTILES; t += 256)
      if (tm[t] <= thresh) {
#pragma unroll
        for (int g = 0; g < 8; ++g) {
          float gv = groupMin[(size_t)(t * 8 + g) * 512 + q];
          if (gv <= thresh) { int p = atomicAdd(&cnt, 1); if (p < LCAP) list[p] = t * 8 + g; }
        }
      }
  } else {
    for (int t = tid; t < NTILES; t += 256)
      if (tm[t] <= thresh) { int p = atomicAdd(&cnt, 1); if (p < LCAP) list[p] = t; }
  }
  __syncthreads();
  const int nl = min(cnt, LCAP);

  double bestK = 1e300; int bestN = 0x7FFFFFFF;
  if (groupMin) {
    // batches of 8 groups = 128 rows; 2 threads per row
    for (int li = 0; li < nl; li += 8) {
      const int idx = li + (tid >> 5);
      if (idx < nl) {
        const int grp = list[idx];
        const int rowin = (tid >> 1) & 15, half = tid & 1;
        const int n = grp * 16 + rowin;
        if (n < NROWS) {
          const float* r = cb + (size_t)n * CDIM;
          double dot = 0.0, sq = 0.0;
          for (int u = half * 32; u < half * 32 + 32; ++u) {
            float4 cv = *(const float4*)(r + u * 4);
            dot += (double)cv.x * csh[u*4+0] + (double)cv.y * csh[u*4+1]
                 + (double)cv.z * csh[u*4+2] + (double)cv.w * csh[u*4+3];
            sq  += (double)cv.x * cv.x + (double)cv.y * cv.y
                 + (double)cv.z * cv.z + (double)cv.w * cv.w;
          }
          dot += __shfl_xor(dot, 1);
          sq  += __shfl_xor(sq, 1);
          double key = sq - 2.0 * dot;
          if (key < bestK || (key == bestK && n < bestN)) { bestK = key; bestN = n; }
        }
      }
    }
  } else {
    for (int li = 0; li < nl; ++li) {
      const int t = list[li];
      const int row = tid >> 1, half = tid & 1;
      const int n = t * NB + row;
      if (n < NROWS) {
        const float* r = cb + (size_t)n * CDIM;
        double dot = 0.0, sq = 0.0;
        for (int u = half * 32; u < half * 32 + 32; ++u) {
          float4 cv = *(const float4*)(r + u * 4);
          dot += (double)cv.x * csh[u*4+0] + (double)cv.y * csh[u*4+1]
               + (double)cv.z * csh[u*4+2] + (double)cv.w * csh[u*4+3];
          sq  += (double)cv.x * cv.x + (double)cv.y * cv.y
               + (double)cv.z * cv.z + (double)cv.w * cv.w;
        }
        dot += __shfl_xor(dot, 1);
        sq  += __shfl_xor(sq, 1);
        double key = sq - 2.0 * dot;
        if (key < bestK || (key == bestK && n < bestN)) { bestK = key; bestN = n; }
      }
    }
  }
  rd[tid] = bestK; rn[tid] = bestN;
  __syncthreads();
  for (int s = 128; s; s >>= 1) {
    if (tid < s) {
      if (rd[tid + s] < rd[tid] || (rd[tid + s] == rd[tid] && rn[tid + s] < rn[tid])) {
        rd[tid] = rd[tid + s]; rn[tid] = rn[tid + s];
      }
    }
    __syncthreads();
  }
  const int nstar = rn[0];
  prev[(size_t)q * CDIM + tid] = cb[(size_t)nstar * CDIM + tid];
}

// ---------------------------------------------------------------- K3: MLP GEMM (up to 3 jobs via blockIdx.z)
struct Job {
  const float* A1; const float* A2; const float* A3;
  const float* W;  const float* bias; float* out;
};

__global__ __launch_bounds__(256) void k_gemm(
    Job j0, Job j1, Job j2, int Kdim, int Ntot, int do_tanh)
{
  __shared__ unsigned short Ash[128 * LDB];
  __shared__ unsigned short Wsh[64 * LDB];
  __shared__ float bsh[64];

  const Job jb = (blockIdx.z == 0) ? j0 : ((blockIdx.z == 1) ? j1 : j2);
  const float* __restrict__ A1 = jb.A1;
  const float* __restrict__ A2 = jb.A2;
  const float* __restrict__ A3 = jb.A3;
  const float* __restrict__ W  = jb.W;

  const int tid  = threadIdx.x;
  const int lane = tid & 63;
  const int w    = tid >> 6;
  const int quad = lane >> 4;
  const int l15  = lane & 15;
  const int q0   = blockIdx.x * 128;
  const int n0   = blockIdx.y * 64;

  if (tid < 64) bsh[tid] = jb.bias[n0 + tid];

  f32x4 acc[2][4];
#pragma unroll
  for (int m = 0; m < 2; ++m)
#pragma unroll
    for (int j = 0; j < 4; ++j) acc[m][j] = (f32x4){0.f, 0.f, 0.f, 0.f};

  for (int kc = 0; kc < Kdim; kc += 256) {
    __syncthreads();
#pragma unroll 4
    for (int it = 0; it < 32; ++it) {
      int i = it * 256 + tid;
      int row = i >> 6, c4 = i & 63;
      size_t gi = (size_t)(q0 + row) * Kdim + kc + c4 * 4;
      float4 v = *(const float4*)(A1 + gi);
      if (A2) { float4 u = *(const float4*)(A2 + gi); v.x += u.x; v.y += u.y; v.z += u.z; v.w += u.w; }
      if (A3) { float4 u = *(const float4*)(A3 + gi); v.x += u.x; v.y += u.y; v.z += u.z; v.w += u.w; }
      uint2 p; p.x = bfp2(v.x, v.y); p.y = bfp2(v.z, v.w);
      *(uint2*)&Ash[row * LDB + c4 * 4] = p;
    }
#pragma unroll 4
    for (int it = 0; it < 16; ++it) {
      int i = it * 256 + tid;
      int row = i >> 6, c4 = i & 63;
      size_t gi = (size_t)(n0 + row) * Kdim + kc + c4 * 4;
      float4 v = *(const float4*)(W + gi);
      uint2 p; p.x = bfp2(v.x, v.y); p.y = bfp2(v.z, v.w);
      *(uint2*)&Wsh[row * LDB + c4 * 4] = p;
    }
    __syncthreads();
#pragma unroll
    for (int ks = 0; ks < 8; ++ks) {
      const int kb = ks * 32 + quad * 8;
      bf16x8 a[2], b[4];
#pragma unroll
      for (int m = 0; m < 2; ++m)
        a[m] = *(const bf16x8*)&Ash[(w * 32 + m * 16 + l15) * LDB + kb];
#pragma unroll
      for (int j = 0; j < 4; ++j)
        b[j] = *(const bf16x8*)&Wsh[(j * 16 + l15) * LDB + kb];
#pragma unroll
      for (int m = 0; m < 2; ++m)
#pragma unroll
        for (int j = 0; j < 4; ++j)
          acc[m][j] = __builtin_amdgcn_mfma_f32_16x16x32_bf16(a[m], b[j], acc[m][j], 0, 0, 0);
    }
  }

#pragma unroll
  for (int m = 0; m < 2; ++m)
#pragma unroll
    for (int j = 0; j < 4; ++j)
#pragma unroll
      for (int r = 0; r < 4; ++r) {
        int q = q0 + w * 32 + m * 16 + quad * 4 + r;
        int n = j * 16 + l15;
        float v = acc[m][j][r] + bsh[n];
        if (do_tanh) v = tanhf(v);
        jb.out[(size_t)q * Ntot + n0 + n] = v;
      }
}

// ---------------------------------------------------------------- launch
extern "C" void kernel_launch(void* const* d_in, const int* in_sizes, int n_in,
                              void* d_out, int out_size, void* d_ws, size_t ws_size,
                              hipStream_t stream) {
  const float* codes = (const float*)d_in[0];
  const float* cb    = (const float*)d_in[1];
  const float* w_in  = (const float*)d_in[2];
  const float* b_in  = (const float*)d_in[3];
  const float* w_h1  = (const float*)d_in[4];
  const float* b_h1  = (const float*)d_in[5];
  const float* w_s2  = (const float*)d_in[6];
  const float* b_s2  = (const float*)d_in[7];
  const float* w_s3  = (const float*)d_in[8];
  const float* b_s3  = (const float*)d_in[9];
  const float* w_h2  = (const float*)d_in[10];
  const float* b_h2  = (const float*)d_in[11];
  const float* w_s1o = (const float*)d_in[12];
  const float* b_s1o = (const float*)d_in[13];
  const float* w_s2o = (const float*)d_in[14];
  const float* b_s2o = (const float*)d_in[15];
  const float* w_h3  = (const float*)d_in[16];
  const float* b_h3  = (const float*)d_in[17];
  const float* w_mu  = (const float*)d_in[18];
  const float* b_mu  = (const float*)d_in[19];
  const float* w_s   = (const float*)d_in[20];
  const float* b_s   = (const float*)d_in[21];
  float* out = (float*)d_out;

  char* ws = (char*)d_ws;
  unsigned short* a0s = (unsigned short*)ws;                     // 262,144 B
  float* tileMin = (float*)(ws + 262144);                        // 8,001,536 B
  float* prev    = (float*)(ws + 262144 + 8001536);              // 524,288 B
  float* acts    = (float*)(ws + 262144 + 8001536 + 524288);     // 8 x 2 MiB
  const int ACT = 512 * 1024;
  float* act_i  = acts + 0 * ACT;
  float* act_h1 = acts + 1 * ACT;
  float* act_s2 = acts + 2 * ACT;
  float* act_s3 = acts + 3 * ACT;
  float* act_h2 = acts + 4 * ACT;
  float* act_o1 = acts + 5 * ACT;
  float* act_o2 = acts + 6 * ACT;
  float* act_o3 = acts + 7 * ACT;

  // bf16 codebook chunk buffer + c2 + groupMin after the legacy 25.5 MB region
  const size_t CBH_OFF = 262144 + 8001536 + 524288 + 16777216;   // 25,565,184
  const size_t CBH_SZ  = (size_t)C0_R * 512;                     // 128,057,344
  const size_t C2_OFF  = CBH_OFF + CBH_SZ;
  const size_t C2_SZ   = (size_t)C0_R * 4;                       // 1,000,448
  const size_t GM_OFF  = C2_OFF + C2_SZ;
  const size_t GM_SZ   = (size_t)NGRP * 512 * 4;                 // 64,012,288
  const size_t NEED    = GM_OFF + GM_SZ;                         // ~219 MB
  unsigned short* cbh = (unsigned short*)(ws + CBH_OFF);
  float* c2buf        = (float*)(ws + C2_OFF);
  float* gmin         = (float*)(ws + GM_OFF);

  hipLaunchKernelGGL(k_prep, dim3(512), dim3(256), 0, stream, codes, a0s);

  bool use_groups = (ws_size >= NEED);
  if (use_groups) {
    // chunk 0
    hipLaunchKernelGGL(k_conv,   dim3(2048), dim3(256), 0, stream, cb, cbh, c2buf, 0, C0_R);
    hipLaunchKernelGGL(k_coarse, dim3(256),  dim3(512), 0, stream, a0s, cbh, c2buf, tileMin, gmin, 0, C0_T);
    // chunk 1
    hipLaunchKernelGGL(k_conv,   dim3(2048), dim3(256), 0, stream, cb, cbh, c2buf, C0_R, C1_R);
    hipLaunchKernelGGL(k_coarse, dim3(256),  dim3(512), 0, stream, a0s, cbh, c2buf, tileMin, gmin, C0_T, C1_T);
  } else {
    hipLaunchKernelGGL(k_coarse_fb, dim3(NTILES), dim3(256), 0, stream, a0s, cb, tileMin);
  }

  hipLaunchKernelGGL(k_refine, dim3(512), dim3(256), 0, stream, codes, cb, tileMin,
                     use_groups ? gmin : (const float*)nullptr, prev);

  const float* NUL = nullptr;
  Job in_j  = { prev,   NUL,    NUL,    w_in,  b_in,  act_i  };
  Job h1_j  = { act_i,  NUL,    NUL,    w_h1,  b_h1,  act_h1 };
  Job s2_j  = { act_h1, NUL,    NUL,    w_s2,  b_s2,  act_s2 };
  Job s3_j  = { act_h1, NUL,    NUL,    w_s3,  b_s3,  act_s3 };
  Job o1_j  = { act_h1, NUL,    NUL,    w_s1o, b_s1o, act_o1 };
  Job h2_j  = { act_h1, act_s2, NUL,    w_h2,  b_h2,  act_h2 };
  Job o2_j  = { act_h2, NUL,    NUL,    w_s2o, b_s2o, act_o2 };
  Job o3_j  = { act_h2, act_s3, NUL,    w_h3,  b_h3,  act_o3 };
  Job mu_j  = { act_o1, act_o2, act_o3, w_mu,  b_mu,  out            };
  Job ls_j  = { act_o1, act_o2, act_o3, w_s,   b_s,   out + 131072   };

  hipLaunchKernelGGL(k_gemm, dim3(4, 16, 1), dim3(256), 0, stream, in_j, in_j, in_j, 256,  1024, 1);
  hipLaunchKernelGGL(k_gemm, dim3(4, 16, 1), dim3(256), 0, stream, h1_j, h1_j, h1_j, 1024, 1024, 1);
  hipLaunchKernelGGL(k_gemm, dim3(4, 16, 3), dim3(256), 0, stream, s2_j, s3_j, o1_j, 1024, 1024, 1);
  hipLaunchKernelGGL(k_gemm, dim3(4, 16, 1), dim3(256), 0, stream, h2_j, h2_j, h2_j, 1024, 1024, 1);
  hipLaunchKernelGGL(k_gemm, dim3(4, 16, 2), dim3(256), 0, stream, o2_j, o3_j, o3_j, 1024, 1024, 1);
  hipLaunchKernelGGL(k_gemm, dim3(4, 4, 2),  dim3(256), 0, stream, mu_j, ls_j, ls_j, 1024, 256,  0);
}